// Round 1
// baseline (1437.496 us; speedup 1.0000x reference)
//
#include <hip/hip_runtime.h>
#include <stdint.h>

#define B_ 8
#define S_ 4096
#define D_ 192
#define M_ (B_*S_)

typedef short v8s __attribute__((ext_vector_type(8)));
typedef float v4f __attribute__((ext_vector_type(4)));

static __device__ __forceinline__ unsigned short f2bf(float f){
  union{float f; unsigned u;} v; v.f=f;
  unsigned u = v.u;
  unsigned r = (u + 0x7fffu + ((u>>16)&1u))>>16;
  return (unsigned short)r;
}

// ---------------- weight conversion fp32 -> bf16 ----------------
__global__ void cvt_w_kernel(const float* w0,const float* w1,const float* w2,const float* w3,
                             const float* w4,const float* w5,const float* w6,const float* w7,
                             unsigned short* dst){
  int w = blockIdx.y;
  const float* src;
  switch(w){
    case 0: src=w0; break; case 1: src=w1; break; case 2: src=w2; break; case 3: src=w3; break;
    case 4: src=w4; break; case 5: src=w5; break; case 6: src=w6; break; default: src=w7; break;
  }
  int i = blockIdx.x*256 + threadIdx.x;   // 36864 = 144*256 exact
  dst[(size_t)w*36864 + i] = f2bf(src[i]);
}

// ---------------- QKV projection: out = x @ W^T (bf16 MFMA) ----------------
// grid: (M/64, 3).  y selects {Q,K,V}. Each wave computes 16 rows x 192 cols.
__global__ __launch_bounds__(256) void proj_kernel(
    const float* __restrict__ x, const unsigned short* __restrict__ Wb,
    unsigned short* __restrict__ Q, unsigned short* __restrict__ K, unsigned short* __restrict__ V,
    int w_off_q, int w_off_k, int w_off_v)
{
  int which = blockIdx.y;
  const unsigned short* W = Wb + (which==0? w_off_q : which==1? w_off_k : w_off_v);
  unsigned short* dst = which==0? Q : (which==1? K : V);
  int tid = threadIdx.x;
  int wid = tid>>6, lane = tid&63;
  int lr = lane&15, lg = lane>>4, kb = lg*8;
  int m0 = blockIdx.x*64 + wid*16;
  int row = m0 + lr;

  // A fragments: x row, converted to bf16 in-register
  v8s a[6];
  #pragma unroll
  for(int c=0;c<6;c++){
    const float* xp = &x[(size_t)row*D_ + c*32 + kb];
    float4 f0 = *(const float4*)xp;
    float4 f1 = *(const float4*)(xp+4);
    v8s t;
    t[0]=(short)f2bf(f0.x); t[1]=(short)f2bf(f0.y); t[2]=(short)f2bf(f0.z); t[3]=(short)f2bf(f0.w);
    t[4]=(short)f2bf(f1.x); t[5]=(short)f2bf(f1.y); t[6]=(short)f2bf(f1.z); t[7]=(short)f2bf(f1.w);
    a[c]=t;
  }
  #pragma unroll
  for(int nt=0; nt<12; nt++){
    v4f acc = {0.f,0.f,0.f,0.f};
    int n = nt*16 + lr;
    #pragma unroll
    for(int c=0;c<6;c++){
      v8s b = *(const v8s*)&W[(size_t)n*D_ + c*32 + kb];
      acc = __builtin_amdgcn_mfma_f32_16x16x32_bf16(a[c], b, acc, 0,0,0);
    }
    int r0 = m0 + lg*4;
    int col = nt*16 + lr;
    #pragma unroll
    for(int r=0;r<4;r++) dst[(size_t)(r0+r)*D_ + col] = f2bf(acc[r]);
  }
}

// ---------------- flash attention ----------------
// grid: (S/64, B).  Block = 64 q rows, 4 waves x 16 rows. KV tiles of 64.
#define KSTR 200
#define VSTR 72
#define PSTR 72

__global__ __launch_bounds__(256) void attn_kernel(
   const unsigned short* __restrict__ Q,
   const unsigned short* __restrict__ K,
   const unsigned short* __restrict__ V,
   unsigned short* __restrict__ O)
{
  __shared__ __align__(16) unsigned short Klds[64*KSTR];
  __shared__ __align__(16) unsigned short Vt[192*VSTR];
  __shared__ __align__(16) unsigned short Plds[4*16*PSTR];

  int b = blockIdx.y;
  int q0 = blockIdx.x*64;
  int tid = threadIdx.x, wid=tid>>6, lane=tid&63;
  int lr = lane&15, lg = lane>>4, kb = lg*8;
  size_t bbase = (size_t)b*S_*D_;

  v8s qf[6];
  {
    size_t qrow = bbase + (size_t)(q0 + wid*16 + lr)*D_;
    #pragma unroll
    for(int c=0;c<6;c++) qf[c] = *(const v8s*)&Q[qrow + c*32 + kb];
  }
  float mrow[4], lsum[4];
  v4f oacc[12];
  #pragma unroll
  for(int r=0;r<4;r++){ mrow[r]=-3.0e38f; lsum[r]=0.f; }
  #pragma unroll
  for(int e=0;e<12;e++) oacc[e] = (v4f){0.f,0.f,0.f,0.f};

  const float scale = 0.07216878364870323f;  // 1/sqrt(192)

  for(int kt=0; kt<64; kt++){
    size_t kvbase = bbase + (size_t)(kt*64)*D_;
    __syncthreads();   // previous compute done before overwriting LDS
    for(int i=tid; i<1536; i+=256){
      int r = i/24, c8 = (i%24)*8;
      v8s kv = *(const v8s*)&K[kvbase + (size_t)r*D_ + c8];
      *(v8s*)&Klds[r*KSTR + c8] = kv;
      v8s vv = *(const v8s*)&V[kvbase + (size_t)r*D_ + c8];
      #pragma unroll
      for(int j=0;j<8;j++) Vt[(c8+j)*VSTR + r] = (unsigned short)(unsigned)(vv[j] & 0xFFFF);
    }
    __syncthreads();

    // scores S = Q @ K^T  (16 q-rows x 64 kv-cols per wave)
    v4f sacc[4];
    #pragma unroll
    for(int ct=0; ct<4; ct++){
      v4f s = {0.f,0.f,0.f,0.f};
      #pragma unroll
      for(int c=0;c<6;c++){
        v8s kf = *(const v8s*)&Klds[(ct*16+lr)*KSTR + c*32 + kb];
        s = __builtin_amdgcn_mfma_f32_16x16x32_bf16(qf[c], kf, s, 0,0,0);
      }
      #pragma unroll
      for(int r=0;r<4;r++) s[r] *= scale;
      sacc[ct]=s;
    }

    // online softmax (row r lives in register r of every lane of the quarter)
    float fac[4];
    #pragma unroll
    for(int r=0;r<4;r++){
      float mt = fmaxf(fmaxf(sacc[0][r],sacc[1][r]),fmaxf(sacc[2][r],sacc[3][r]));
      #pragma unroll
      for(int msk=1; msk<16; msk<<=1) mt = fmaxf(mt, __shfl_xor(mt, msk, 64));
      float mn = fmaxf(mrow[r], mt);
      fac[r] = __expf(mrow[r]-mn);
      mrow[r] = mn;
      float ps = 0.f;
      #pragma unroll
      for(int ct=0;ct<4;ct++){
        float p = __expf(sacc[ct][r]-mn);
        ps += p;
        Plds[(wid*16 + lg*4 + r)*PSTR + ct*16 + lr] = f2bf(p);
      }
      #pragma unroll
      for(int msk=1; msk<16; msk<<=1) ps += __shfl_xor(ps, msk, 64);
      lsum[r] = lsum[r]*fac[r] + ps;
    }
    #pragma unroll
    for(int e=0;e<12;e++){
      #pragma unroll
      for(int r=0;r<4;r++) oacc[e][r]*=fac[r];
    }

    // O += P @ V   (A-frag from per-wave Plds, B-frag from transposed Vt)
    #pragma unroll
    for(int e=0;e<12;e++){
      #pragma unroll
      for(int kc=0;kc<2;kc++){
        v8s pa = *(const v8s*)&Plds[(wid*16 + lr)*PSTR + kc*32 + kb];
        v8s vb = *(const v8s*)&Vt[(e*16+lr)*VSTR + kc*32 + kb];
        oacc[e] = __builtin_amdgcn_mfma_f32_16x16x32_bf16(pa, vb, oacc[e], 0,0,0);
      }
    }
  }

  #pragma unroll
  for(int r=0;r<4;r++) lsum[r] = 1.0f/lsum[r];
  size_t orow0 = bbase + (size_t)(q0 + wid*16 + lg*4)*D_;
  #pragma unroll
  for(int e=0;e<12;e++){
    #pragma unroll
    for(int r=0;r<4;r++){
      O[orow0 + (size_t)r*D_ + e*16 + lr] = f2bf(oacc[e][r]*lsum[r]);
    }
  }
}

// ---------------- final: R = O @ Wo^T (both), combine, column fixes ----------------
__global__ __launch_bounds__(256) void final_kernel(
  const float* __restrict__ x,
  const unsigned short* __restrict__ Or,
  const unsigned short* __restrict__ Ow,
  const unsigned short* __restrict__ WoR,
  const unsigned short* __restrict__ WoW,
  float* __restrict__ out)
{
  int tid=threadIdx.x, wid=tid>>6, lane=tid&63;
  int lr=lane&15, lg=lane>>4, kb=lg*8;
  int m0 = blockIdx.x*64 + wid*16;
  int arow = m0 + lr;
  v8s ar[6], aw[6];
  #pragma unroll
  for(int c=0;c<6;c++){
    ar[c] = *(const v8s*)&Or[(size_t)arow*D_ + c*32 + kb];
    aw[c] = *(const v8s*)&Ow[(size_t)arow*D_ + c*32 + kb];
  }
  int bidx = m0 / S_;
  float rf = x[(size_t)bidx*S_*D_ + 156];
  float wf = x[(size_t)bidx*S_*D_ + 157];
  #pragma unroll
  for(int nt=0; nt<12; nt++){
    v4f accR={0.f,0.f,0.f,0.f}, accW={0.f,0.f,0.f,0.f};
    int n = nt*16 + lr;
    #pragma unroll
    for(int c=0;c<6;c++){
      v8s br = *(const v8s*)&WoR[(size_t)n*D_ + c*32 + kb];
      accR = __builtin_amdgcn_mfma_f32_16x16x32_bf16(ar[c], br, accR,0,0,0);
      v8s bw = *(const v8s*)&WoW[(size_t)n*D_ + c*32 + kb];
      accW = __builtin_amdgcn_mfma_f32_16x16x32_bf16(aw[c], bw, accW,0,0,0);
    }
    #pragma unroll
    for(int r=0;r<4;r++){
      int row = m0 + lg*4 + r;
      int col = nt*16 + lr;
      float xv = x[(size_t)row*D_ + col];
      float val = xv + rf*(accR[r]-xv) + wf*(accW[r]-xv);
      if(col==156||col==157) val = 0.f;
      else if(col==158) val = rf+wf;
      out[(size_t)row*D_ + col] = val;
    }
  }
}

extern "C" void kernel_launch(void* const* d_in, const int* in_sizes, int n_in,
                              void* d_out, int out_size, void* d_ws, size_t ws_size,
                              hipStream_t stream) {
  const float* x = (const float*)d_in[0];
  unsigned short* ws = (unsigned short*)d_ws;
  const size_t WSZ = 36864;           // 192*192
  const size_t MD  = (size_t)M_*D_;   // 32768*192
  unsigned short* Wb = ws;            // 8 * WSZ
  unsigned short* Qb = ws + 8*WSZ;
  unsigned short* Kb = Qb + MD;
  unsigned short* Vb = Kb + MD;
  unsigned short* Or = Vb + MD;
  unsigned short* Ow = Or + MD;

  cvt_w_kernel<<<dim3(144,8),256,0,stream>>>(
      (const float*)d_in[1],(const float*)d_in[2],(const float*)d_in[3],(const float*)d_in[4],
      (const float*)d_in[5],(const float*)d_in[6],(const float*)d_in[7],(const float*)d_in[8], Wb);

  // read path
  proj_kernel<<<dim3(512,3),256,0,stream>>>(x, Wb, Qb,Kb,Vb, 0*36864, 1*36864, 2*36864);
  attn_kernel<<<dim3(64,8),256,0,stream>>>(Qb,Kb,Vb,Or);
  // write path (reuse QKV buffers)
  proj_kernel<<<dim3(512,3),256,0,stream>>>(x, Wb, Qb,Kb,Vb, 4*36864, 5*36864, 6*36864);
  attn_kernel<<<dim3(64,8),256,0,stream>>>(Qb,Kb,Vb,Ow);

  final_kernel<<<512,256,0,stream>>>(x, Or, Ow, Wb+3*36864, Wb+7*36864, (float*)d_out);
}

// Round 2
// 819.379 us; speedup vs baseline: 1.7544x; 1.7544x over previous
//
#include <hip/hip_runtime.h>
#include <stdint.h>

#define B_ 8
#define S_ 4096
#define D_ 192
#define M_ (B_*S_)

typedef short v8s __attribute__((ext_vector_type(8)));
typedef float v4f __attribute__((ext_vector_type(4)));
typedef unsigned short v4us __attribute__((ext_vector_type(4)));

static __device__ __forceinline__ unsigned short f2bf(float f){
  union{float f; unsigned u;} v; v.f=f;
  unsigned u = v.u;
  unsigned r = (u + 0x7fffu + ((u>>16)&1u))>>16;
  return (unsigned short)r;
}

// ---------------- weight conversion fp32 -> bf16 ----------------
__global__ void cvt_w_kernel(const float* w0,const float* w1,const float* w2,const float* w3,
                             const float* w4,const float* w5,const float* w6,const float* w7,
                             unsigned short* dst){
  int w = blockIdx.y;
  const float* src;
  switch(w){
    case 0: src=w0; break; case 1: src=w1; break; case 2: src=w2; break; case 3: src=w3; break;
    case 4: src=w4; break; case 5: src=w5; break; case 6: src=w6; break; default: src=w7; break;
  }
  int i = blockIdx.x*256 + threadIdx.x;   // 36864 = 144*256 exact
  dst[(size_t)w*36864 + i] = f2bf(src[i]);
}

// ---------------- QKV projection: out = x @ W^T (bf16 MFMA) ----------------
// grid: (M/64, 3). y selects {Q,K,V}. V is stored TRANSPOSED per batch: Vt[b][d][s].
__global__ __launch_bounds__(256) void proj_kernel(
    const float* __restrict__ x, const unsigned short* __restrict__ Wb,
    unsigned short* __restrict__ Q, unsigned short* __restrict__ K, unsigned short* __restrict__ Vt,
    int w_off_q, int w_off_k, int w_off_v)
{
  int which = blockIdx.y;
  const unsigned short* W = Wb + (which==0? w_off_q : which==1? w_off_k : w_off_v);
  int tid = threadIdx.x;
  int wid = tid>>6, lane = tid&63;
  int lr = lane&15, lg = lane>>4, kb = lg*8;
  int m0 = blockIdx.x*64 + wid*16;
  int row = m0 + lr;

  v8s a[6];
  #pragma unroll
  for(int c=0;c<6;c++){
    const float* xp = &x[(size_t)row*D_ + c*32 + kb];
    float4 f0 = *(const float4*)xp;
    float4 f1 = *(const float4*)(xp+4);
    v8s t;
    t[0]=(short)f2bf(f0.x); t[1]=(short)f2bf(f0.y); t[2]=(short)f2bf(f0.z); t[3]=(short)f2bf(f0.w);
    t[4]=(short)f2bf(f1.x); t[5]=(short)f2bf(f1.y); t[6]=(short)f2bf(f1.z); t[7]=(short)f2bf(f1.w);
    a[c]=t;
  }
  int bidx = m0 / S_;
  int s0 = (m0 % S_) + lg*4;
  #pragma unroll
  for(int nt=0; nt<12; nt++){
    v4f acc = {0.f,0.f,0.f,0.f};
    int n = nt*16 + lr;
    #pragma unroll
    for(int c=0;c<6;c++){
      v8s b = *(const v8s*)&W[(size_t)n*D_ + c*32 + kb];
      acc = __builtin_amdgcn_mfma_f32_16x16x32_bf16(a[c], b, acc, 0,0,0);
    }
    int col = nt*16 + lr;
    if(which==2){
      // transposed store: Vt[(b*D + col)*S + s0 .. +3]  (8B packed)
      v4us pk;
      pk[0]=f2bf(acc[0]); pk[1]=f2bf(acc[1]); pk[2]=f2bf(acc[2]); pk[3]=f2bf(acc[3]);
      *(v4us*)&Vt[((size_t)bidx*D_ + col)*S_ + s0] = pk;
    } else {
      unsigned short* dst = which==0? Q : K;
      int r0 = m0 + lg*4;
      #pragma unroll
      for(int r=0;r<4;r++) dst[(size_t)(r0+r)*D_ + col] = f2bf(acc[r]);
    }
  }
}

// ---------------- flash attention ----------------
// grid: (S/128, B). Block = 128 q rows, 4 waves x 32 rows. KV tiles of 64.
#define KSTR 200
#define VSTR 72
#define PSTR 68

__global__ __launch_bounds__(256) void attn_kernel(
   const unsigned short* __restrict__ Q,
   const unsigned short* __restrict__ K,
   const unsigned short* __restrict__ Vtg,
   unsigned short* __restrict__ O)
{
  __shared__ __align__(16) unsigned short Klds[64*KSTR];   // 25600 B; P aliases here after QK
  __shared__ __align__(16) unsigned short Vlds[192*VSTR];  // 27648 B

  int b = blockIdx.y;
  int q0 = blockIdx.x*128;
  int tid = threadIdx.x, wid=tid>>6, lane=tid&63;
  int lr = lane&15, lg = lane>>4, kb = lg*8;
  size_t bbase = (size_t)b*S_*D_;
  int qrow0 = q0 + wid*32;

  v8s qf[2][6];
  #pragma unroll
  for(int h=0;h<2;h++){
    size_t qrow = bbase + (size_t)(qrow0 + h*16 + lr)*D_;
    #pragma unroll
    for(int c=0;c<6;c++) qf[h][c] = *(const v8s*)&Q[qrow + c*32 + kb];
  }
  float mrow[2][4], lsum[2][4];
  v4f oacc[2][12];
  #pragma unroll
  for(int h=0;h<2;h++){
    #pragma unroll
    for(int r=0;r<4;r++){ mrow[h][r]=-3.0e38f; lsum[h][r]=0.f; }
    #pragma unroll
    for(int e=0;e<12;e++) oacc[h][e] = (v4f){0.f,0.f,0.f,0.f};
  }

  const float scale = 0.07216878364870323f;  // 1/sqrt(192)
  const size_t vbase = (size_t)b*D_*S_;      // Vt[b][d][s]
  unsigned short* Pw = Klds + wid*32*PSTR;

  for(int kt=0; kt<64; kt++){
    size_t kvbase = bbase + (size_t)(kt*64)*D_;
    __syncthreads();   // prev iter's LDS reads complete
    #pragma unroll
    for(int i=tid; i<1536; i+=256){
      int r = i/24, c8 = (i%24)*8;
      *(v8s*)&Klds[r*KSTR + c8] = *(const v8s*)&K[kvbase + (size_t)r*D_ + c8];
      int vr = i>>3, vc = (i&7)*8;
      *(v8s*)&Vlds[vr*VSTR + vc] = *(const v8s*)&Vtg[vbase + (size_t)vr*S_ + kt*64 + vc];
    }
    __syncthreads();

    // scores: both q-halves share each K fragment read
    v4f sacc[2][4];
    #pragma unroll
    for(int ct=0; ct<4; ct++){
      v4f s0v = {0.f,0.f,0.f,0.f}, s1v = {0.f,0.f,0.f,0.f};
      #pragma unroll
      for(int c=0;c<6;c++){
        v8s kf = *(const v8s*)&Klds[(ct*16+lr)*KSTR + c*32 + kb];
        s0v = __builtin_amdgcn_mfma_f32_16x16x32_bf16(qf[0][c], kf, s0v, 0,0,0);
        s1v = __builtin_amdgcn_mfma_f32_16x16x32_bf16(qf[1][c], kf, s1v, 0,0,0);
      }
      #pragma unroll
      for(int r=0;r<4;r++){ s0v[r]*=scale; s1v[r]*=scale; }
      sacc[0][ct]=s0v; sacc[1][ct]=s1v;
    }
    __syncthreads();   // all QK reads of Klds done before P overwrites it

    float fac[2][4];
    #pragma unroll
    for(int h=0;h<2;h++){
      #pragma unroll
      for(int r=0;r<4;r++){
        float mt = fmaxf(fmaxf(sacc[h][0][r],sacc[h][1][r]),fmaxf(sacc[h][2][r],sacc[h][3][r]));
        #pragma unroll
        for(int msk=1; msk<16; msk<<=1) mt = fmaxf(mt, __shfl_xor(mt, msk, 64));
        float mn = fmaxf(mrow[h][r], mt);
        fac[h][r] = __expf(mrow[h][r]-mn);
        mrow[h][r] = mn;
        float ps = 0.f;
        #pragma unroll
        for(int ct=0;ct<4;ct++){
          float p = __expf(sacc[h][ct][r]-mn);
          ps += p;
          Pw[(h*16 + lg*4 + r)*PSTR + ct*16 + lr] = f2bf(p);
        }
        #pragma unroll
        for(int msk=1; msk<16; msk<<=1) ps += __shfl_xor(ps, msk, 64);
        lsum[h][r] = lsum[h][r]*fac[h][r] + ps;
      }
    }
    #pragma unroll
    for(int h=0;h<2;h++){
      #pragma unroll
      for(int e=0;e<12;e++){
        #pragma unroll
        for(int r=0;r<4;r++) oacc[h][e][r]*=fac[h][r];
      }
    }

    // O += P @ V^T-tile : P-frags hoisted, V-frag shared by both halves
    v8s pa[2][2];
    #pragma unroll
    for(int h=0;h<2;h++){
      #pragma unroll
      for(int kc=0;kc<2;kc++)
        pa[h][kc] = *(const v8s*)&Pw[(h*16 + lr)*PSTR + kc*32 + kb];
    }
    #pragma unroll
    for(int e=0;e<12;e++){
      #pragma unroll
      for(int kc=0;kc<2;kc++){
        v8s vb = *(const v8s*)&Vlds[(e*16+lr)*VSTR + kc*32 + kb];
        oacc[0][e] = __builtin_amdgcn_mfma_f32_16x16x32_bf16(pa[0][kc], vb, oacc[0][e], 0,0,0);
        oacc[1][e] = __builtin_amdgcn_mfma_f32_16x16x32_bf16(pa[1][kc], vb, oacc[1][e], 0,0,0);
      }
    }
  }

  #pragma unroll
  for(int h=0;h<2;h++){
    #pragma unroll
    for(int r=0;r<4;r++) lsum[h][r] = 1.0f/lsum[h][r];
  }
  #pragma unroll
  for(int h=0;h<2;h++){
    size_t orow0 = bbase + (size_t)(qrow0 + h*16 + lg*4)*D_;
    #pragma unroll
    for(int e=0;e<12;e++){
      #pragma unroll
      for(int r=0;r<4;r++){
        O[orow0 + (size_t)r*D_ + e*16 + lr] = f2bf(oacc[h][e][r]*lsum[h][r]);
      }
    }
  }
}

// ---------------- final: R = O @ Wo^T (both), combine, column fixes ----------------
__global__ __launch_bounds__(256) void final_kernel(
  const float* __restrict__ x,
  const unsigned short* __restrict__ Or,
  const unsigned short* __restrict__ Ow,
  const unsigned short* __restrict__ WoR,
  const unsigned short* __restrict__ WoW,
  float* __restrict__ out)
{
  int tid=threadIdx.x, wid=tid>>6, lane=tid&63;
  int lr=lane&15, lg=lane>>4, kb=lg*8;
  int m0 = blockIdx.x*64 + wid*16;
  int arow = m0 + lr;
  v8s ar[6], aw[6];
  #pragma unroll
  for(int c=0;c<6;c++){
    ar[c] = *(const v8s*)&Or[(size_t)arow*D_ + c*32 + kb];
    aw[c] = *(const v8s*)&Ow[(size_t)arow*D_ + c*32 + kb];
  }
  int bidx = m0 / S_;
  float rf = x[(size_t)bidx*S_*D_ + 156];
  float wf = x[(size_t)bidx*S_*D_ + 157];
  #pragma unroll
  for(int nt=0; nt<12; nt++){
    v4f accR={0.f,0.f,0.f,0.f}, accW={0.f,0.f,0.f,0.f};
    int n = nt*16 + lr;
    #pragma unroll
    for(int c=0;c<6;c++){
      v8s br = *(const v8s*)&WoR[(size_t)n*D_ + c*32 + kb];
      accR = __builtin_amdgcn_mfma_f32_16x16x32_bf16(ar[c], br, accR,0,0,0);
      v8s bw = *(const v8s*)&WoW[(size_t)n*D_ + c*32 + kb];
      accW = __builtin_amdgcn_mfma_f32_16x16x32_bf16(aw[c], bw, accW,0,0,0);
    }
    #pragma unroll
    for(int r=0;r<4;r++){
      int row = m0 + lg*4 + r;
      int col = nt*16 + lr;
      float xv = x[(size_t)row*D_ + col];
      float val = xv + rf*(accR[r]-xv) + wf*(accW[r]-xv);
      if(col==156||col==157) val = 0.f;
      else if(col==158) val = rf+wf;
      out[(size_t)row*D_ + col] = val;
    }
  }
}

extern "C" void kernel_launch(void* const* d_in, const int* in_sizes, int n_in,
                              void* d_out, int out_size, void* d_ws, size_t ws_size,
                              hipStream_t stream) {
  const float* x = (const float*)d_in[0];
  unsigned short* ws = (unsigned short*)d_ws;
  const size_t WSZ = 36864;           // 192*192
  const size_t MD  = (size_t)M_*D_;   // 32768*192
  unsigned short* Wb = ws;            // 8 * WSZ
  unsigned short* Qb = ws + 8*WSZ;
  unsigned short* Kb = Qb + MD;
  unsigned short* Vb = Kb + MD;       // transposed layout [B][D][S]
  unsigned short* Or = Vb + MD;
  unsigned short* Ow = Or + MD;

  cvt_w_kernel<<<dim3(144,8),256,0,stream>>>(
      (const float*)d_in[1],(const float*)d_in[2],(const float*)d_in[3],(const float*)d_in[4],
      (const float*)d_in[5],(const float*)d_in[6],(const float*)d_in[7],(const float*)d_in[8], Wb);

  // read path
  proj_kernel<<<dim3(512,3),256,0,stream>>>(x, Wb, Qb,Kb,Vb, 0*36864, 1*36864, 2*36864);
  attn_kernel<<<dim3(32,8),256,0,stream>>>(Qb,Kb,Vb,Or);
  // write path (reuse QKV buffers)
  proj_kernel<<<dim3(512,3),256,0,stream>>>(x, Wb, Qb,Kb,Vb, 4*36864, 5*36864, 6*36864);
  attn_kernel<<<dim3(32,8),256,0,stream>>>(Qb,Kb,Vb,Ow);

  final_kernel<<<512,256,0,stream>>>(x, Or, Ow, Wb+3*36864, Wb+7*36864, (float*)d_out);
}